// Round 1
// baseline (2627.241 us; speedup 1.0000x reference)
//
#include <hip/hip_runtime.h>

typedef unsigned short u16;
typedef __attribute__((ext_vector_type(4))) short short4v;
typedef __attribute__((ext_vector_type(8))) short short8v;
typedef __attribute__((ext_vector_type(4))) unsigned short ushort4v;
typedef __attribute__((ext_vector_type(4))) float float4v;

#define GLOAD16(ldsp, gp)                                                      \
  __builtin_amdgcn_global_load_lds(                                            \
      (const __attribute__((address_space(1))) unsigned int*)(gp),             \
      (__attribute__((address_space(3))) unsigned int*)(ldsp), 16, 0, 0)

__device__ __forceinline__ u16 f2bf(float f) {
  union { float f; unsigned u; } v; v.f = f;
  unsigned r = v.u + 0x7fffu + ((v.u >> 16) & 1u);
  return (u16)(r >> 16);
}
__device__ __forceinline__ float bf2f(u16 h) {
  union { unsigned u; float f; } v; v.u = ((unsigned)h) << 16;
  return v.f;
}
// elu(x)+1 = x+1 (x>0) else exp(x)
__device__ __forceinline__ float fmap(float x) { return x > 0.f ? x + 1.f : __expf(x); }

// ---------------------------------------------------------------------------
// Core 128x128-tile bf16 MFMA GEMM (m97 structure): A row-major [M][K],
// B^T row-major [N][K]; BK=64; 4 waves (2x2 of 64x64); global_load_lds staging.
// A/B fragment k-map: elems 0-3 -> k = 4*(l>>4)+j ; elems 4-7 -> +16.
// C/D: col = l&15, row = 4*(l>>4)+reg (m89-verified).
// ---------------------------------------------------------------------------
__device__ __forceinline__ void gemm_core(
    const u16* __restrict__ A, int lda, const u16* __restrict__ B, int ldb,
    int m0, int n0, int k0, int nsteps, u16* Al, u16* Bl, float4v acc[4][4]) {
  const int lane = threadIdx.x & 63;
  const int wid  = threadIdx.x >> 6;
  const int wr = wid >> 1, wc = wid & 1;
  const int sr = lane >> 3;          // row-in-8 for staging
  const int sc = (lane & 7) * 8;     // k-offset (elements) for staging
  for (int kt = 0; kt < nsteps; ++kt) {
    const int kb = k0 + kt * 64;
#pragma unroll
    for (int jj = 0; jj < 4; ++jj) {
      const int rb = wid * 8 + jj * 32;   // wave-uniform LDS row base
      GLOAD16(Al + rb * 64, A + (size_t)(m0 + rb + sr) * lda + kb + sc);
      GLOAD16(Bl + rb * 64, B + (size_t)(n0 + rb + sr) * ldb + kb + sc);
    }
    __syncthreads();
#pragma unroll
    for (int kk = 0; kk < 64; kk += 32) {
      short8v af[4], bfr[4];
#pragma unroll
      for (int i = 0; i < 4; ++i) {
        const u16* pa = Al + (wr * 64 + i * 16 + (lane & 15)) * 64 + kk + 4 * (lane >> 4);
        short4v a0 = *(const short4v*)pa;
        short4v a1 = *(const short4v*)(pa + 16);
        af[i] = __builtin_shufflevector(a0, a1, 0, 1, 2, 3, 4, 5, 6, 7);
        const u16* pb = Bl + (wc * 64 + i * 16 + (lane & 15)) * 64 + kk + 4 * (lane >> 4);
        short4v b0 = *(const short4v*)pb;
        short4v b1 = *(const short4v*)(pb + 16);
        bfr[i] = __builtin_shufflevector(b0, b1, 0, 1, 2, 3, 4, 5, 6, 7);
      }
#pragma unroll
      for (int i = 0; i < 4; ++i)
#pragma unroll
        for (int j = 0; j < 4; ++j)
          acc[i][j] = __builtin_amdgcn_mfma_f32_16x16x32_bf16(af[i], bfr[j], acc[i][j], 0, 0, 0);
    }
    __syncthreads();
  }
}

#define ZERO_ACC(acc)                                            \
  _Pragma("unroll") for (int i_ = 0; i_ < 4; ++i_)               \
  _Pragma("unroll") for (int j_ = 0; j_ < 4; ++j_)               \
      acc[i_][j_] = (float4v){0.f, 0.f, 0.f, 0.f};

// ---------------------------------------------------------------------------
// fp32 -> bf16 convert of x (32768x1024)
// ---------------------------------------------------------------------------
__global__ void __launch_bounds__(256) k_conv(const float* __restrict__ in,
                                              u16* __restrict__ out) {
  const int i = blockIdx.x * 256 + threadIdx.x;   // index over float4s, 8388608 total
  float4v v = ((const float4v*)in)[i];
  ushort4v o;
  o[0] = f2bf(v[0]); o[1] = f2bf(v[1]); o[2] = f2bf(v[2]); o[3] = f2bf(v[3]);
  *(ushort4v*)(out + (size_t)i * 4) = o;
}

// ---------------------------------------------------------------------------
// transpose+convert weights: in [R][C] f32 -> out [C][R] bf16 (64x64 LDS tiles)
// ---------------------------------------------------------------------------
__global__ void __launch_bounds__(256) k_transpose(const float* __restrict__ in,
                                                   u16* __restrict__ out, int R, int C) {
  __shared__ u16 tile[64][65];
  const int nbc = C >> 6;
  const int bc = blockIdx.x % nbc, br = blockIdx.x / nbc;
  const int r0 = br * 64, c0 = bc * 64;
  const int t = threadIdx.x;
  const int lr = t >> 4;          // 0..15
  const int lc = (t & 15) * 4;    // 0..60
#pragma unroll
  for (int p = 0; p < 4; ++p) {
    const int r = p * 16 + lr;
    float4v v = *(const float4v*)(in + (size_t)(r0 + r) * C + c0 + lc);
    tile[r][lc + 0] = f2bf(v[0]); tile[r][lc + 1] = f2bf(v[1]);
    tile[r][lc + 2] = f2bf(v[2]); tile[r][lc + 3] = f2bf(v[3]);
  }
  __syncthreads();
#pragma unroll
  for (int p = 0; p < 4; ++p) {
    const int c = p * 16 + lr;
    ushort4v o;
    o[0] = tile[lc + 0][c]; o[1] = tile[lc + 1][c];
    o[2] = tile[lc + 2][c]; o[3] = tile[lc + 3][c];
    *(ushort4v*)(out + (size_t)(c0 + c) * R + r0 + lc) = o;
  }
}

// ---------------------------------------------------------------------------
// GEMM1: h1 = x@W1 + b1. cols 0-1023 -> q (fmap, [n][1024] bf16)
//        cols 1024-2047 -> k (fmap, transposed [dim][N] bf16)
//        cols 2048-3071 -> non_att (fp32, straight into d_out)
// ---------------------------------------------------------------------------
__global__ void __launch_bounds__(256) k_gemm1(
    const u16* __restrict__ xb, const u16* __restrict__ w1t,
    const float* __restrict__ bias1, u16* __restrict__ qbuf,
    u16* __restrict__ ktb, float* __restrict__ dout) {
  __shared__ u16 Al[128 * 64], Bl[128 * 64];
  const int mt = blockIdx.x / 24, nt = blockIdx.x % 24;
  float4v acc[4][4];
  ZERO_ACC(acc);
  gemm_core(xb, 1024, w1t, 1024, mt * 128, nt * 128, 0, 16, Al, Bl, acc);
  const int lane = threadIdx.x & 63, wid = threadIdx.x >> 6;
  const int wr = wid >> 1, wc = wid & 1;
  const int region = nt >> 3;     // 0:q 1:k 2:non_att (block-uniform)
#pragma unroll
  for (int i = 0; i < 4; ++i) {
    const int rb = mt * 128 + wr * 64 + i * 16 + 4 * (lane >> 4);
#pragma unroll
    for (int j = 0; j < 4; ++j) {
      const int cg = nt * 128 + wc * 64 + j * 16 + (lane & 15);
      const float bia = bias1[cg];
      if (region == 0) {
#pragma unroll
        for (int r = 0; r < 4; ++r)
          qbuf[(size_t)(rb + r) * 1024 + cg] = f2bf(fmap(acc[i][j][r] + bia));
      } else if (region == 1) {
        const int rc = cg - 1024;
        ushort4v pk;
#pragma unroll
        for (int r = 0; r < 4; ++r) pk[r] = f2bf(fmap(acc[i][j][r] + bia));
        *(ushort4v*)(ktb + (size_t)rc * 32768 + rb) = pk;   // [dim][N]
      } else {
        const int rc = cg - 2048;
#pragma unroll
        for (int r = 0; r < 4; ++r)
          dout[(size_t)(rb + r) * 1024 + rc] = acc[i][j][r] + bia;
      }
    }
  }
}

// ---------------------------------------------------------------------------
// GEMM2: v = x@Wv + bv -> transposed [dim][N] bf16
// ---------------------------------------------------------------------------
__global__ void __launch_bounds__(256) k_gemm2(
    const u16* __restrict__ xb, const u16* __restrict__ wvt,
    const float* __restrict__ biasv, u16* __restrict__ vtb) {
  __shared__ u16 Al[128 * 64], Bl[128 * 64];
  const int mt = blockIdx.x / 8, nt = blockIdx.x % 8;
  float4v acc[4][4];
  ZERO_ACC(acc);
  gemm_core(xb, 1024, wvt, 1024, mt * 128, nt * 128, 0, 16, Al, Bl, acc);
  const int lane = threadIdx.x & 63, wid = threadIdx.x >> 6;
  const int wr = wid >> 1, wc = wid & 1;
#pragma unroll
  for (int i = 0; i < 4; ++i) {
    const int rb = mt * 128 + wr * 64 + i * 16 + 4 * (lane >> 4);
#pragma unroll
    for (int j = 0; j < 4; ++j) {
      const int cg = nt * 128 + wc * 64 + j * 16 + (lane & 15);
      const float bia = biasv[cg];
      ushort4v pk;
#pragma unroll
      for (int r = 0; r < 4; ++r) pk[r] = f2bf(acc[i][j][r] + bia);
      *(ushort4v*)(vtb + (size_t)cg * 32768 + rb) = pk;     // [dim][N]
    }
  }
}

// ---------------------------------------------------------------------------
// kv partials: per (head, K-chunk of 1024): kv_part = k_chunk^T-GEMM (128x128)
// part layout [h][chunk][kd][vd] fp32
// ---------------------------------------------------------------------------
__global__ void __launch_bounds__(256) k_kvpart(
    const u16* __restrict__ ktb, const u16* __restrict__ vtb, float* __restrict__ part) {
  __shared__ u16 Al[128 * 64], Bl[128 * 64];
  const int h = blockIdx.x >> 5, ch = blockIdx.x & 31;
  float4v acc[4][4];
  ZERO_ACC(acc);
  gemm_core(ktb + (size_t)h * 128 * 32768, 32768,
            vtb + (size_t)h * 128 * 32768, 32768, 0, 0, ch * 1024, 16, Al, Bl, acc);
  float* o = part + (size_t)(h * 32 + ch) * 16384;
  const int lane = threadIdx.x & 63, wid = threadIdx.x >> 6;
  const int wr = wid >> 1, wc = wid & 1;
#pragma unroll
  for (int i = 0; i < 4; ++i) {
    const int rb = wr * 64 + i * 16 + 4 * (lane >> 4);
#pragma unroll
    for (int j = 0; j < 4; ++j) {
      const int cg = wc * 64 + j * 16 + (lane & 15);
#pragma unroll
      for (int r = 0; r < 4; ++r) o[(size_t)(rb + r) * 128 + cg] = acc[i][j][r];
    }
  }
}

// ---------------------------------------------------------------------------
// reduce kv partials over 32 chunks; store TRANSPOSED kv_t [h][vd][kd] bf16
// ---------------------------------------------------------------------------
__global__ void __launch_bounds__(128) k_kvred(const float* __restrict__ part,
                                               u16* __restrict__ kvt) {
  const int b = blockIdx.x;           // h*128 + kd
  const int h = b >> 7, kd = b & 127;
  const int vd = threadIdx.x;         // 128 threads
  const float* p = part + (size_t)h * 32 * 16384 + (size_t)kd * 128 + vd;
  float s = 0.f;
#pragma unroll
  for (int c = 0; c < 32; ++c) s += p[(size_t)c * 16384];
  kvt[(size_t)(h * 128 + vd) * 128 + kd] = f2bf(s);
}

// ---------------------------------------------------------------------------
// k_sum[h][d] = sum_n k_t[h][d][n]   (row reduction of [dim][N] layout)
// ---------------------------------------------------------------------------
__global__ void __launch_bounds__(256) k_ksum(const u16* __restrict__ ktb,
                                              float* __restrict__ ksum) {
  const int b = blockIdx.x;           // h*128 + d  (row of ktb)
  const int t = threadIdx.x;
  const u16* row = ktb + (size_t)b * 32768;
  float s = 0.f;
#pragma unroll
  for (int i = 0; i < 16; ++i) {
    short8v v = *(const short8v*)(row + (size_t)(i * 256 + t) * 8);
#pragma unroll
    for (int e = 0; e < 8; ++e) s += bf2f((u16)v[e]);
  }
  __shared__ float red[256];
  red[t] = s;
  __syncthreads();
  for (int off = 128; off > 0; off >>= 1) {
    if (t < off) red[t] += red[t + off];
    __syncthreads();
  }
  if (t == 0) ksum[b] = red[0];
}

// ---------------------------------------------------------------------------
// att = (q @ kv) / (q . k_sum), per (head, 128-row tile). K = 128 (full head).
// Writes att bf16 over the q buffer (each block owns its exact region).
// ---------------------------------------------------------------------------
__global__ void __launch_bounds__(256) k_attn(
    const u16* __restrict__ q, const u16* __restrict__ kvt,
    const float* __restrict__ ksum, u16* __restrict__ att) {
  __shared__ u16 qlds[128 * 128];
  __shared__ u16 blds[128 * 128];
  __shared__ float ksl[128];
  __shared__ float qkl[128];
  const int b = blockIdx.x;
  const int h = b >> 8, nt = b & 255;
  const int n0 = nt * 128;
  const int tid = threadIdx.x, lane = tid & 63, wid = tid >> 6;
  const int wr = wid >> 1, wc = wid & 1;
  const int sr = lane >> 4;            // 0..3 (4 rows per call, 256B rows)
  const int sc = (lane & 15) * 8;
#pragma unroll
  for (int jj = 0; jj < 8; ++jj) {
    const int rb = wid * 32 + jj * 4;
    GLOAD16(qlds + rb * 128, q + (size_t)(n0 + rb + sr) * 1024 + h * 128 + sc);
    GLOAD16(blds + rb * 128, kvt + (size_t)(h * 128 + rb + sr) * 128 + sc);
  }
  if (tid < 128) ksl[tid] = ksum[h * 128 + tid];
  __syncthreads();
  // qk_sum per row (threads 0..127, rotated start to dodge bank conflicts)
  if (tid < 128) {
    float s = 0.f;
    const int rot = tid & 15;
#pragma unroll
    for (int ii = 0; ii < 16; ++ii) {
      const int d8 = ((rot + ii) & 15) * 8;
      short8v v = *(const short8v*)&qlds[tid * 128 + d8];
#pragma unroll
      for (int e = 0; e < 8; ++e) s += bf2f((u16)v[e]) * ksl[d8 + e];
    }
    qkl[tid] = (s == 0.f) ? 1e-5f : s;
  }
  float4v acc[4][4];
  ZERO_ACC(acc);
#pragma unroll
  for (int kk = 0; kk < 128; kk += 32) {
    short8v af[4], bfr[4];
#pragma unroll
    for (int i = 0; i < 4; ++i) {
      const u16* pa = qlds + (wr * 64 + i * 16 + (lane & 15)) * 128 + kk + 4 * (lane >> 4);
      short4v a0 = *(const short4v*)pa;
      short4v a1 = *(const short4v*)(pa + 16);
      af[i] = __builtin_shufflevector(a0, a1, 0, 1, 2, 3, 4, 5, 6, 7);
      const u16* pb = blds + (wc * 64 + i * 16 + (lane & 15)) * 128 + kk + 4 * (lane >> 4);
      short4v b0 = *(const short4v*)pb;
      short4v b1 = *(const short4v*)(pb + 16);
      bfr[i] = __builtin_shufflevector(b0, b1, 0, 1, 2, 3, 4, 5, 6, 7);
    }
#pragma unroll
    for (int i = 0; i < 4; ++i)
#pragma unroll
      for (int j = 0; j < 4; ++j)
        acc[i][j] = __builtin_amdgcn_mfma_f32_16x16x32_bf16(af[i], bfr[j], acc[i][j], 0, 0, 0);
  }
  __syncthreads();   // qkl visible to all
#pragma unroll
  for (int i = 0; i < 4; ++i) {
    const int rl = wr * 64 + i * 16 + 4 * (lane >> 4);
#pragma unroll
    for (int j = 0; j < 4; ++j) {
      const int cl = wc * 64 + j * 16 + (lane & 15);
#pragma unroll
      for (int r = 0; r < 4; ++r) {
        const float v = acc[i][j][r] / qkl[rl + r];
        att[(size_t)(n0 + rl + r) * 1024 + h * 128 + cl] = f2bf(v);
      }
    }
  }
}

// ---------------------------------------------------------------------------
// out = non_att(already in d_out) + att@Wo + bo
// ---------------------------------------------------------------------------
__global__ void __launch_bounds__(256) k_gemmo(
    const u16* __restrict__ attb, const u16* __restrict__ wot,
    const float* __restrict__ biaso, float* __restrict__ dout) {
  __shared__ u16 Al[128 * 64], Bl[128 * 64];
  const int mt = blockIdx.x / 8, nt = blockIdx.x % 8;
  float4v acc[4][4];
  ZERO_ACC(acc);
  gemm_core(attb, 1024, wot, 1024, mt * 128, nt * 128, 0, 16, Al, Bl, acc);
  const int lane = threadIdx.x & 63, wid = threadIdx.x >> 6;
  const int wr = wid >> 1, wc = wid & 1;
#pragma unroll
  for (int i = 0; i < 4; ++i) {
    const int rb = mt * 128 + wr * 64 + i * 16 + 4 * (lane >> 4);
#pragma unroll
    for (int j = 0; j < 4; ++j) {
      const int cg = nt * 128 + wc * 64 + j * 16 + (lane & 15);
      const float bia = biaso[cg];
#pragma unroll
      for (int r = 0; r < 4; ++r) {
        const size_t idx = (size_t)(rb + r) * 1024 + cg;
        dout[idx] = dout[idx] + acc[i][j][r] + bia;
      }
    }
  }
}

// ---------------------------------------------------------------------------
extern "C" void kernel_launch(void* const* d_in, const int* in_sizes, int n_in,
                              void* d_out, int out_size, void* d_ws, size_t ws_size,
                              hipStream_t stream) {
  const float* x  = (const float*)d_in[0];
  const float* W1 = (const float*)d_in[1];
  const float* b1 = (const float*)d_in[2];
  const float* Wv = (const float*)d_in[3];
  const float* bv = (const float*)d_in[4];
  const float* Wo = (const float*)d_in[5];
  const float* bo = (const float*)d_in[6];
  float* out = (float*)d_out;

  const size_t N = 32768;
  u16* xb  = (u16*)d_ws;                    // x bf16 [N][1024]           64 MB
  u16* qb  = xb  + N * 1024;                // q (then att) [N][1024]     64 MB
  u16* ktb = qb  + N * 1024;                // k_t [8*128][N]             64 MB
  u16* vtb = ktb + N * 1024;                // v_t [8*128][N]             64 MB
  u16* w1t = vtb + N * 1024;                // W1^T bf16 [3072][1024]      6 MB
  u16* wvt = w1t + (size_t)3072 * 1024;     // Wv^T bf16                   2 MB
  u16* wot = wvt + (size_t)1024 * 1024;     // Wo^T bf16                   2 MB
  float* part = (float*)(wot + (size_t)1024 * 1024);  // kv partials      16 MB
  u16* kvt = (u16*)(part + (size_t)8 * 32 * 16384);   // kv_t [h][vd][kd] 256 KB
  float* ksum = (float*)(kvt + (size_t)8 * 16384);    // k_sum [8][128]     4 KB

  k_conv<<<32768, 256, 0, stream>>>(x, xb);
  k_transpose<<<768, 256, 0, stream>>>(W1, w1t, 1024, 3072);
  k_transpose<<<256, 256, 0, stream>>>(Wv, wvt, 1024, 1024);
  k_transpose<<<256, 256, 0, stream>>>(Wo, wot, 1024, 1024);
  k_gemm1<<<6144, 256, 0, stream>>>(xb, w1t, b1, qb, ktb, out);
  k_gemm2<<<2048, 256, 0, stream>>>(xb, wvt, bv, vtb);
  k_kvpart<<<256, 256, 0, stream>>>(ktb, vtb, part);
  k_ksum<<<1024, 256, 0, stream>>>(ktb, ksum);
  k_kvred<<<1024, 128, 0, stream>>>(part, kvt);
  k_attn<<<2048, 256, 0, stream>>>(qb, kvt, ksum, qb);
  k_gemmo<<<2048, 256, 0, stream>>>(qb, wot, bo, out);
}

// Round 2
// 762.991 us; speedup vs baseline: 3.4433x; 3.4433x over previous
//
#include <hip/hip_runtime.h>

typedef unsigned short u16;
typedef __attribute__((ext_vector_type(4))) short short4v;
typedef __attribute__((ext_vector_type(8))) short short8v;
typedef __attribute__((ext_vector_type(4))) unsigned short ushort4v;
typedef __attribute__((ext_vector_type(4))) float float4v;

#define GLOAD16(ldsp, gp)                                                      \
  __builtin_amdgcn_global_load_lds(                                            \
      (const __attribute__((address_space(1))) unsigned int*)(gp),             \
      (__attribute__((address_space(3))) unsigned int*)(ldsp), 16, 0, 0)

__device__ __forceinline__ u16 f2bf(float f) {
  union { float f; unsigned u; } v; v.f = f;
  unsigned r = v.u + 0x7fffu + ((v.u >> 16) & 1u);
  return (u16)(r >> 16);
}
__device__ __forceinline__ float bf2f(u16 h) {
  union { unsigned u; float f; } v; v.u = ((unsigned)h) << 16;
  return v.f;
}
// elu(x)+1 = x+1 (x>0) else exp(x)
__device__ __forceinline__ float fmap(float x) { return x > 0.f ? x + 1.f : __expf(x); }

// ---------------------------------------------------------------------------
// Core 128x128-tile bf16 MFMA GEMM (m97 structure + T2 XOR swizzle):
// A row-major [M][K], B^T row-major [N][K]; BK=64; 4 waves (2x2 of 64x64).
// LDS rows are 128B (8 x 16B slots). Physical slot s of row r holds logical
// slot s ^ (r&7):  staging pre-swizzles the GLOBAL source column (LDS dest
// stays linear for global_load_lds), reads XOR the byte column.
// A/B fragment k-map: elems 0-3 -> k = 4*(l>>4)+j ; elems 4-7 -> +16.
// C/D: col = l&15, row = 4*(l>>4)+reg (m89-verified).
// ---------------------------------------------------------------------------
__device__ __forceinline__ void gemm_core(
    const u16* __restrict__ A, int lda, const u16* __restrict__ B, int ldb,
    int m0, int n0, int k0, int nsteps, u16* Al, u16* Bl, float4v acc[4][4]) {
  const int lane = threadIdx.x & 63;
  const int wid  = threadIdx.x >> 6;
  const int wr = wid >> 1, wc = wid & 1;
  const int sr = lane >> 3;                               // row-in-8 for staging
  const int sc = ((lane & 7) ^ (lane >> 3)) * 8;          // PRE-SWIZZLED source col
  const int swz = (lane & 7) << 4;                        // read-side XOR (bytes)
  const int g4 = 4 * (lane >> 4);
  for (int kt = 0; kt < nsteps; ++kt) {
    const int kb = k0 + kt * 64;
#pragma unroll
    for (int jj = 0; jj < 4; ++jj) {
      const int rb = wid * 8 + jj * 32;   // wave-uniform LDS row base (mult of 8)
      GLOAD16(Al + rb * 64, A + (size_t)(m0 + rb + sr) * lda + kb + sc);
      GLOAD16(Bl + rb * 64, B + (size_t)(n0 + rb + sr) * ldb + kb + sc);
    }
    __syncthreads();
#pragma unroll
    for (int kk = 0; kk < 64; kk += 32) {
      const int c0 = 2 * (kk + g4);
      short8v af[4], bfr[4];
#pragma unroll
      for (int i = 0; i < 4; ++i) {
        const char* pa = (const char*)(Al + (wr * 64 + i * 16 + (lane & 15)) * 64);
        short4v a0 = *(const short4v*)(pa + (c0 ^ swz));
        short4v a1 = *(const short4v*)(pa + ((c0 + 32) ^ swz));
        af[i] = __builtin_shufflevector(a0, a1, 0, 1, 2, 3, 4, 5, 6, 7);
        const char* pb = (const char*)(Bl + (wc * 64 + i * 16 + (lane & 15)) * 64);
        short4v b0 = *(const short4v*)(pb + (c0 ^ swz));
        short4v b1 = *(const short4v*)(pb + ((c0 + 32) ^ swz));
        bfr[i] = __builtin_shufflevector(b0, b1, 0, 1, 2, 3, 4, 5, 6, 7);
      }
#pragma unroll
      for (int i = 0; i < 4; ++i)
#pragma unroll
        for (int j = 0; j < 4; ++j)
          acc[i][j] = __builtin_amdgcn_mfma_f32_16x16x32_bf16(af[i], bfr[j], acc[i][j], 0, 0, 0);
    }
    __syncthreads();
  }
}

#define ZERO_ACC(acc)                                            \
  _Pragma("unroll") for (int i_ = 0; i_ < 4; ++i_)               \
  _Pragma("unroll") for (int j_ = 0; j_ < 4; ++j_)               \
      acc[i_][j_] = (float4v){0.f, 0.f, 0.f, 0.f};

// ---------------------------------------------------------------------------
// fp32 -> bf16 convert of x (32768x1024)
// ---------------------------------------------------------------------------
__global__ void __launch_bounds__(256) k_conv(const float* __restrict__ in,
                                              u16* __restrict__ out) {
  const int i = blockIdx.x * 256 + threadIdx.x;   // index over float4s, 8388608 total
  float4v v = ((const float4v*)in)[i];
  ushort4v o;
  o[0] = f2bf(v[0]); o[1] = f2bf(v[1]); o[2] = f2bf(v[2]); o[3] = f2bf(v[3]);
  *(ushort4v*)(out + (size_t)i * 4) = o;
}

// ---------------------------------------------------------------------------
// transpose+convert weights: in [R][C] f32 -> out [C][R] bf16 (64x64 LDS tiles)
// ---------------------------------------------------------------------------
__global__ void __launch_bounds__(256) k_transpose(const float* __restrict__ in,
                                                   u16* __restrict__ out, int R, int C) {
  __shared__ u16 tile[64][65];
  const int nbc = C >> 6;
  const int bc = blockIdx.x % nbc, br = blockIdx.x / nbc;
  const int r0 = br * 64, c0 = bc * 64;
  const int t = threadIdx.x;
  const int lr = t >> 4;          // 0..15
  const int lc = (t & 15) * 4;    // 0..60
#pragma unroll
  for (int p = 0; p < 4; ++p) {
    const int r = p * 16 + lr;
    float4v v = *(const float4v*)(in + (size_t)(r0 + r) * C + c0 + lc);
    tile[r][lc + 0] = f2bf(v[0]); tile[r][lc + 1] = f2bf(v[1]);
    tile[r][lc + 2] = f2bf(v[2]); tile[r][lc + 3] = f2bf(v[3]);
  }
  __syncthreads();
#pragma unroll
  for (int p = 0; p < 4; ++p) {
    const int c = p * 16 + lr;
    ushort4v o;
    o[0] = tile[lc + 0][c]; o[1] = tile[lc + 1][c];
    o[2] = tile[lc + 2][c]; o[3] = tile[lc + 3][c];
    *(ushort4v*)(out + (size_t)(c0 + c) * R + r0 + lc) = o;
  }
}

// ---------------------------------------------------------------------------
// GEMM1: h1 = x@W1 + b1. cols 0-1023 -> q (fmap, [n][1024] bf16)
//        cols 1024-2047 -> k (fmap, transposed [dim][N] bf16)
//        cols 2048-3071 -> non_att (fp32, straight into d_out)
// ---------------------------------------------------------------------------
__global__ void __launch_bounds__(256) k_gemm1(
    const u16* __restrict__ xb, const u16* __restrict__ w1t,
    const float* __restrict__ bias1, u16* __restrict__ qbuf,
    u16* __restrict__ ktb, float* __restrict__ dout) {
  __shared__ u16 Al[128 * 64], Bl[128 * 64];
  const int mt = blockIdx.x / 24, nt = blockIdx.x % 24;
  float4v acc[4][4];
  ZERO_ACC(acc);
  gemm_core(xb, 1024, w1t, 1024, mt * 128, nt * 128, 0, 16, Al, Bl, acc);
  const int lane = threadIdx.x & 63, wid = threadIdx.x >> 6;
  const int wr = wid >> 1, wc = wid & 1;
  const int region = nt >> 3;     // 0:q 1:k 2:non_att (block-uniform)
#pragma unroll
  for (int i = 0; i < 4; ++i) {
    const int rb = mt * 128 + wr * 64 + i * 16 + 4 * (lane >> 4);
#pragma unroll
    for (int j = 0; j < 4; ++j) {
      const int cg = nt * 128 + wc * 64 + j * 16 + (lane & 15);
      const float bia = bias1[cg];
      if (region == 0) {
#pragma unroll
        for (int r = 0; r < 4; ++r)
          qbuf[(size_t)(rb + r) * 1024 + cg] = f2bf(fmap(acc[i][j][r] + bia));
      } else if (region == 1) {
        const int rc = cg - 1024;
        ushort4v pk;
#pragma unroll
        for (int r = 0; r < 4; ++r) pk[r] = f2bf(fmap(acc[i][j][r] + bia));
        *(ushort4v*)(ktb + (size_t)rc * 32768 + rb) = pk;   // [dim][N]
      } else {
        const int rc = cg - 2048;
#pragma unroll
        for (int r = 0; r < 4; ++r)
          dout[(size_t)(rb + r) * 1024 + rc] = acc[i][j][r] + bia;
      }
    }
  }
}

// ---------------------------------------------------------------------------
// GEMM2: v = x@Wv + bv -> transposed [dim][N] bf16
// ---------------------------------------------------------------------------
__global__ void __launch_bounds__(256) k_gemm2(
    const u16* __restrict__ xb, const u16* __restrict__ wvt,
    const float* __restrict__ biasv, u16* __restrict__ vtb) {
  __shared__ u16 Al[128 * 64], Bl[128 * 64];
  const int mt = blockIdx.x / 8, nt = blockIdx.x % 8;
  float4v acc[4][4];
  ZERO_ACC(acc);
  gemm_core(xb, 1024, wvt, 1024, mt * 128, nt * 128, 0, 16, Al, Bl, acc);
  const int lane = threadIdx.x & 63, wid = threadIdx.x >> 6;
  const int wr = wid >> 1, wc = wid & 1;
#pragma unroll
  for (int i = 0; i < 4; ++i) {
    const int rb = mt * 128 + wr * 64 + i * 16 + 4 * (lane >> 4);
#pragma unroll
    for (int j = 0; j < 4; ++j) {
      const int cg = nt * 128 + wc * 64 + j * 16 + (lane & 15);
      const float bia = biasv[cg];
      ushort4v pk;
#pragma unroll
      for (int r = 0; r < 4; ++r) pk[r] = f2bf(acc[i][j][r] + bia);
      *(ushort4v*)(vtb + (size_t)cg * 32768 + rb) = pk;     // [dim][N]
    }
  }
}

// ---------------------------------------------------------------------------
// kv partials: per (head, K-chunk of 1024): kv_part = k_chunk^T-GEMM (128x128)
// part layout [h][chunk][kd][vd] fp32
// ---------------------------------------------------------------------------
__global__ void __launch_bounds__(256) k_kvpart(
    const u16* __restrict__ ktb, const u16* __restrict__ vtb, float* __restrict__ part) {
  __shared__ u16 Al[128 * 64], Bl[128 * 64];
  const int h = blockIdx.x >> 5, ch = blockIdx.x & 31;
  float4v acc[4][4];
  ZERO_ACC(acc);
  gemm_core(ktb + (size_t)h * 128 * 32768, 32768,
            vtb + (size_t)h * 128 * 32768, 32768, 0, 0, ch * 1024, 16, Al, Bl, acc);
  float* o = part + (size_t)(h * 32 + ch) * 16384;
  const int lane = threadIdx.x & 63, wid = threadIdx.x >> 6;
  const int wr = wid >> 1, wc = wid & 1;
#pragma unroll
  for (int i = 0; i < 4; ++i) {
    const int rb = wr * 64 + i * 16 + 4 * (lane >> 4);
#pragma unroll
    for (int j = 0; j < 4; ++j) {
      const int cg = wc * 64 + j * 16 + (lane & 15);
#pragma unroll
      for (int r = 0; r < 4; ++r) o[(size_t)(rb + r) * 128 + cg] = acc[i][j][r];
    }
  }
}

// ---------------------------------------------------------------------------
// reduce kv partials over 32 chunks; store TRANSPOSED kv_t [h][vd][kd] bf16
// ---------------------------------------------------------------------------
__global__ void __launch_bounds__(128) k_kvred(const float* __restrict__ part,
                                               u16* __restrict__ kvt) {
  const int b = blockIdx.x;           // h*128 + kd
  const int h = b >> 7, kd = b & 127;
  const int vd = threadIdx.x;         // 128 threads
  const float* p = part + (size_t)h * 32 * 16384 + (size_t)kd * 128 + vd;
  float s = 0.f;
#pragma unroll
  for (int c = 0; c < 32; ++c) s += p[(size_t)c * 16384];
  kvt[(size_t)(h * 128 + vd) * 128 + kd] = f2bf(s);
}

// ---------------------------------------------------------------------------
// k_sum[h][d] = sum_n k_t[h][d][n]   (row reduction of [dim][N] layout)
// ---------------------------------------------------------------------------
__global__ void __launch_bounds__(256) k_ksum(const u16* __restrict__ ktb,
                                              float* __restrict__ ksum) {
  const int b = blockIdx.x;           // h*128 + d  (row of ktb)
  const int t = threadIdx.x;
  const u16* row = ktb + (size_t)b * 32768;
  float s = 0.f;
#pragma unroll
  for (int i = 0; i < 16; ++i) {
    short8v v = *(const short8v*)(row + (size_t)(i * 256 + t) * 8);
#pragma unroll
    for (int e = 0; e < 8; ++e) s += bf2f((u16)v[e]);
  }
  __shared__ float red[256];
  red[t] = s;
  __syncthreads();
  for (int off = 128; off > 0; off >>= 1) {
    if (t < off) red[t] += red[t + off];
    __syncthreads();
  }
  if (t == 0) ksum[b] = red[0];
}

// ---------------------------------------------------------------------------
// att = (q @ kv) / (q . k_sum), per (head, 128-row tile). K = 128 (full head).
// LDS rows are 256B (16 x 16B slots): physical slot s of row r holds logical
// slot s ^ (r&15). Staging pre-swizzles the global source; reads XOR bytes.
// ---------------------------------------------------------------------------
__global__ void __launch_bounds__(256) k_attn(
    const u16* __restrict__ q, const u16* __restrict__ kvt,
    const float* __restrict__ ksum, u16* __restrict__ att) {
  __shared__ u16 qlds[128 * 128];
  __shared__ u16 blds[128 * 128];
  __shared__ float ksl[128];
  __shared__ float qkl[128];
  const int b = blockIdx.x;
  const int h = b >> 8, nt = b & 255;
  const int n0 = nt * 128;
  const int tid = threadIdx.x, lane = tid & 63, wid = tid >> 6;
  const int wr = wid >> 1, wc = wid & 1;
  const int sr = lane >> 4;            // 0..3 (4 rows per call, 256B rows)
#pragma unroll
  for (int jj = 0; jj < 8; ++jj) {
    const int rb = wid * 32 + jj * 4;
    const int srcslot = (lane & 15) ^ ((rb + (lane >> 4)) & 15);   // pre-swizzle
    GLOAD16(qlds + rb * 128, q + (size_t)(n0 + rb + sr) * 1024 + h * 128 + srcslot * 8);
    GLOAD16(blds + rb * 128, kvt + (size_t)(h * 128 + rb + sr) * 128 + srcslot * 8);
  }
  if (tid < 128) ksl[tid] = ksum[h * 128 + tid];
  __syncthreads();
  // qk_sum per row (threads 0..127), reading swizzled slots
  if (tid < 128) {
    float s = 0.f;
    const int rsw = tid & 15;
#pragma unroll
    for (int ii = 0; ii < 16; ++ii) {
      const int slot = ii ^ rsw;       // physical slot holding logical slot ii
      short8v v = *(const short8v*)((const char*)qlds + tid * 256 + slot * 16);
#pragma unroll
      for (int e = 0; e < 8; ++e) s += bf2f((u16)v[e]) * ksl[ii * 8 + e];
    }
    qkl[tid] = (s == 0.f) ? 1e-5f : s;
  }
  float4v acc[4][4];
  ZERO_ACC(acc);
  const int swz = (lane & 15) << 4;
  const int g4 = 4 * (lane >> 4);
#pragma unroll
  for (int kk = 0; kk < 128; kk += 32) {
    const int c0 = 2 * (kk + g4);
    short8v af[4], bfr[4];
#pragma unroll
    for (int i = 0; i < 4; ++i) {
      const char* pa = (const char*)(qlds + (wr * 64 + i * 16 + (lane & 15)) * 128);
      short4v a0 = *(const short4v*)(pa + (c0 ^ swz));
      short4v a1 = *(const short4v*)(pa + ((c0 + 32) ^ swz));
      af[i] = __builtin_shufflevector(a0, a1, 0, 1, 2, 3, 4, 5, 6, 7);
      const char* pb = (const char*)(blds + (wc * 64 + i * 16 + (lane & 15)) * 128);
      short4v b0 = *(const short4v*)(pb + (c0 ^ swz));
      short4v b1 = *(const short4v*)(pb + ((c0 + 32) ^ swz));
      bfr[i] = __builtin_shufflevector(b0, b1, 0, 1, 2, 3, 4, 5, 6, 7);
    }
#pragma unroll
    for (int i = 0; i < 4; ++i)
#pragma unroll
      for (int j = 0; j < 4; ++j)
        acc[i][j] = __builtin_amdgcn_mfma_f32_16x16x32_bf16(af[i], bfr[j], acc[i][j], 0, 0, 0);
  }
  __syncthreads();   // qkl visible to all
#pragma unroll
  for (int i = 0; i < 4; ++i) {
    const int rl = wr * 64 + i * 16 + 4 * (lane >> 4);
#pragma unroll
    for (int j = 0; j < 4; ++j) {
      const int cl = wc * 64 + j * 16 + (lane & 15);
#pragma unroll
      for (int r = 0; r < 4; ++r) {
        const float v = acc[i][j][r] / qkl[rl + r];
        att[(size_t)(n0 + rl + r) * 1024 + h * 128 + cl] = f2bf(v);
      }
    }
  }
}

// ---------------------------------------------------------------------------
// out = non_att(already in d_out) + att@Wo + bo
// ---------------------------------------------------------------------------
__global__ void __launch_bounds__(256) k_gemmo(
    const u16* __restrict__ attb, const u16* __restrict__ wot,
    const float* __restrict__ biaso, float* __restrict__ dout) {
  __shared__ u16 Al[128 * 64], Bl[128 * 64];
  const int mt = blockIdx.x / 8, nt = blockIdx.x % 8;
  float4v acc[4][4];
  ZERO_ACC(acc);
  gemm_core(attb, 1024, wot, 1024, mt * 128, nt * 128, 0, 16, Al, Bl, acc);
  const int lane = threadIdx.x & 63, wid = threadIdx.x >> 6;
  const int wr = wid >> 1, wc = wid & 1;
#pragma unroll
  for (int i = 0; i < 4; ++i) {
    const int rb = mt * 128 + wr * 64 + i * 16 + 4 * (lane >> 4);
#pragma unroll
    for (int j = 0; j < 4; ++j) {
      const int cg = nt * 128 + wc * 64 + j * 16 + (lane & 15);
      const float bia = biaso[cg];
#pragma unroll
      for (int r = 0; r < 4; ++r) {
        const size_t idx = (size_t)(rb + r) * 1024 + cg;
        dout[idx] = dout[idx] + acc[i][j][r] + bia;
      }
    }
  }
}

// ---------------------------------------------------------------------------
extern "C" void kernel_launch(void* const* d_in, const int* in_sizes, int n_in,
                              void* d_out, int out_size, void* d_ws, size_t ws_size,
                              hipStream_t stream) {
  const float* x  = (const float*)d_in[0];
  const float* W1 = (const float*)d_in[1];
  const float* b1 = (const float*)d_in[2];
  const float* Wv = (const float*)d_in[3];
  const float* bv = (const float*)d_in[4];
  const float* Wo = (const float*)d_in[5];
  const float* bo = (const float*)d_in[6];
  float* out = (float*)d_out;

  const size_t N = 32768;
  u16* xb  = (u16*)d_ws;                    // x bf16 [N][1024]           64 MB
  u16* qb  = xb  + N * 1024;                // q (then att) [N][1024]     64 MB
  u16* ktb = qb  + N * 1024;                // k_t [8*128][N]             64 MB
  u16* vtb = ktb + N * 1024;                // v_t [8*128][N]             64 MB
  u16* w1t = vtb + N * 1024;                // W1^T bf16 [3072][1024]      6 MB
  u16* wvt = w1t + (size_t)3072 * 1024;     // Wv^T bf16                   2 MB
  u16* wot = wvt + (size_t)1024 * 1024;     // Wo^T bf16                   2 MB
  float* part = (float*)(wot + (size_t)1024 * 1024);  // kv partials      16 MB
  u16* kvt = (u16*)(part + (size_t)8 * 32 * 16384);   // kv_t [h][vd][kd] 256 KB
  float* ksum = (float*)(kvt + (size_t)8 * 16384);    // k_sum [8][128]     4 KB

  k_conv<<<32768, 256, 0, stream>>>(x, xb);
  k_transpose<<<768, 256, 0, stream>>>(W1, w1t, 1024, 3072);
  k_transpose<<<256, 256, 0, stream>>>(Wv, wvt, 1024, 1024);
  k_transpose<<<256, 256, 0, stream>>>(Wo, wot, 1024, 1024);
  k_gemm1<<<6144, 256, 0, stream>>>(xb, w1t, b1, qb, ktb, out);
  k_gemm2<<<2048, 256, 0, stream>>>(xb, wvt, bv, vtb);
  k_kvpart<<<256, 256, 0, stream>>>(ktb, vtb, part);
  k_ksum<<<1024, 256, 0, stream>>>(ktb, ksum);
  k_kvred<<<1024, 128, 0, stream>>>(part, kvt);
  k_attn<<<2048, 256, 0, stream>>>(qb, kvt, ksum, qb);
  k_gemmo<<<2048, 256, 0, stream>>>(qb, wot, bo, out);
}

// Round 3
// 602.414 us; speedup vs baseline: 4.3612x; 1.2666x over previous
//
#include <hip/hip_runtime.h>

typedef unsigned short u16;
typedef __attribute__((ext_vector_type(4))) short short4v;
typedef __attribute__((ext_vector_type(8))) short short8v;
typedef __attribute__((ext_vector_type(4))) unsigned short ushort4v;
typedef __attribute__((ext_vector_type(4))) float float4v;

#define GLOAD16(ldsp, gp)                                                      \
  __builtin_amdgcn_global_load_lds(                                            \
      (const __attribute__((address_space(1))) unsigned int*)(gp),             \
      (__attribute__((address_space(3))) unsigned int*)(ldsp), 16, 0, 0)

__device__ __forceinline__ u16 f2bf(float f) {
  union { float f; unsigned u; } v; v.f = f;
  unsigned r = v.u + 0x7fffu + ((v.u >> 16) & 1u);
  return (u16)(r >> 16);
}
__device__ __forceinline__ float bf2f(u16 h) {
  union { unsigned u; float f; } v; v.u = ((unsigned)h) << 16;
  return v.f;
}
__device__ __forceinline__ float fmap(float x) { return x > 0.f ? x + 1.f : __expf(x); }

// k-permutation: storage position 8g+j (within a 32-block) holds k = 4g + (j<4? j : 12+j).
// Makes each MFMA A/B fragment (lanegroup g, kk-block b) one contiguous 16B at slot 4b+g.
__device__ __forceinline__ int permp(int k) {
  const int r5 = k & 31;
  const int p = (r5 < 16) ? ((r5 >> 2) * 8 + (r5 & 3))
                          : (((r5 - 16) >> 2) * 8 + 4 + ((r5 - 16) & 3));
  return (k & ~31) + p;
}

// ======================= old 2-phase core (kvpart only) ======================
__device__ __forceinline__ void gemm_core(
    const u16* __restrict__ A, int lda, const u16* __restrict__ B, int ldb,
    int m0, int n0, int k0, int nsteps, u16* Al, u16* Bl, float4v acc[4][4]) {
  const int lane = threadIdx.x & 63;
  const int wid  = threadIdx.x >> 6;
  const int wr = wid >> 1, wc = wid & 1;
  const int sr = lane >> 3;
  const int sc = ((lane & 7) ^ (lane >> 3)) * 8;
  const int swz = (lane & 7) << 4;
  const int g4 = 4 * (lane >> 4);
  for (int kt = 0; kt < nsteps; ++kt) {
    const int kb = k0 + kt * 64;
#pragma unroll
    for (int jj = 0; jj < 4; ++jj) {
      const int rb = wid * 8 + jj * 32;
      GLOAD16(Al + rb * 64, A + (size_t)(m0 + rb + sr) * lda + kb + sc);
      GLOAD16(Bl + rb * 64, B + (size_t)(n0 + rb + sr) * ldb + kb + sc);
    }
    __syncthreads();
#pragma unroll
    for (int kk = 0; kk < 64; kk += 32) {
      const int c0 = 2 * (kk + g4);
      short8v af[4], bfr[4];
#pragma unroll
      for (int i = 0; i < 4; ++i) {
        const char* pa = (const char*)(Al + (wr * 64 + i * 16 + (lane & 15)) * 64);
        short4v a0 = *(const short4v*)(pa + (c0 ^ swz));
        short4v a1 = *(const short4v*)(pa + ((c0 + 32) ^ swz));
        af[i] = __builtin_shufflevector(a0, a1, 0, 1, 2, 3, 4, 5, 6, 7);
        const char* pb = (const char*)(Bl + (wc * 64 + i * 16 + (lane & 15)) * 64);
        short4v b0 = *(const short4v*)(pb + (c0 ^ swz));
        short4v b1 = *(const short4v*)(pb + ((c0 + 32) ^ swz));
        bfr[i] = __builtin_shufflevector(b0, b1, 0, 1, 2, 3, 4, 5, 6, 7);
      }
#pragma unroll
      for (int i = 0; i < 4; ++i)
#pragma unroll
        for (int j = 0; j < 4; ++j)
          acc[i][j] = __builtin_amdgcn_mfma_f32_16x16x32_bf16(af[i], bfr[j], acc[i][j], 0, 0, 0);
    }
    __syncthreads();
  }
}

#define ZERO_ACC4(acc)                                           \
  _Pragma("unroll") for (int i_ = 0; i_ < 4; ++i_)               \
  _Pragma("unroll") for (int j_ = 0; j_ < 4; ++j_)               \
      acc[i_][j_] = (float4v){0.f, 0.f, 0.f, 0.f};

// ===================== 256x256 8-phase core (T2+T3+T4+T5) ====================
// A,B row-major [*][1024] k-PERMUTED; tile 256x256, BK=64, 8 waves (2Mx4N),
// per-wave 128x64 out = acc[8][4]. LDS: 2 dbuf x (A 256x64 + B 256x64) = 128KB.
// Phase p computes mreps {2p-2,2p-1} x all 4 nreps x kk{0,32} = 16 MFMA.
// B frags for a tile are read once (phase 1/5). Staging ledger (iter i,
// T0=2i->buf0, T1=2i+1->buf1, t2=2i+2, t3=2i+3), 2 gloads per phase:
//  ph1: T1.A{1,3}  ph2: t2.B{0,1}  ph3: t2.B{2,3}  ph4: t2.A{0,2} +vmcnt(6)
//  ph5: t2.A{1,3}  ph6: t3.B{0,1}  ph7: t3.B{2,3}  ph8: t3.A{0,2} +vmcnt(6)
// Every overwrite lands >=1 barrier after its region's last read (ledger in
// round notes). vmcnt(6): exactly 3 units (6 loads) issued after the needed
// tile's last load. Last iteration: vmcnt(0) at ph4 (no trailing issues).
#define FRAG(tile, row, slog)                                                  \
  (*(const short8v*)((const char*)(tile) + (row) * 128 + ((((slog) ^ ((row) & 7))) * 16)))

#define BAR()                                                                  \
  do { asm volatile("" ::: "memory"); __builtin_amdgcn_s_barrier();            \
       __builtin_amdgcn_sched_barrier(0); asm volatile("" ::: "memory"); } while (0)

#define WAITVM6() asm volatile("s_waitcnt vmcnt(6)" ::: "memory")
#define WAITVM0() asm volatile("s_waitcnt vmcnt(0)" ::: "memory")

#define READA(Asrc, m0)                                                        \
  aF0  = FRAG(Asrc, wr * 128 + (m0) * 16 + l15, g);                            \
  aF0k = FRAG(Asrc, wr * 128 + (m0) * 16 + l15, 4 + g);                        \
  aF1  = FRAG(Asrc, wr * 128 + (m0) * 16 + 16 + l15, g);                       \
  aF1k = FRAG(Asrc, wr * 128 + (m0) * 16 + 16 + l15, 4 + g);

#define READB(Bsrc)                                                            \
  _Pragma("unroll") for (int j_ = 0; j_ < 4; ++j_) {                           \
    bF[0][j_] = FRAG(Bsrc, wc * 64 + j_ * 16 + l15, g);                        \
    bF[1][j_] = FRAG(Bsrc, wc * 64 + j_ * 16 + l15, 4 + g);                    \
  }

#define MFMA16(m0)                                                             \
  __builtin_amdgcn_s_setprio(1);                                               \
  _Pragma("unroll") for (int j_ = 0; j_ < 4; ++j_) {                           \
    acc[(m0)][j_]     = __builtin_amdgcn_mfma_f32_16x16x32_bf16(aF0,  bF[0][j_], acc[(m0)][j_], 0, 0, 0);     \
    acc[(m0) + 1][j_] = __builtin_amdgcn_mfma_f32_16x16x32_bf16(aF1,  bF[0][j_], acc[(m0) + 1][j_], 0, 0, 0); \
  }                                                                            \
  _Pragma("unroll") for (int j_ = 0; j_ < 4; ++j_) {                           \
    acc[(m0)][j_]     = __builtin_amdgcn_mfma_f32_16x16x32_bf16(aF0k, bF[1][j_], acc[(m0)][j_], 0, 0, 0);     \
    acc[(m0) + 1][j_] = __builtin_amdgcn_mfma_f32_16x16x32_bf16(aF1k, bF[1][j_], acc[(m0) + 1][j_], 0, 0, 0); \
  }                                                                            \
  __builtin_amdgcn_s_setprio(0);

#define STA(bufptr, c, t) GLOAD16((bufptr) + (c) * 4096 + ldsw, A + (size_t)(c) * 64 * 1024 + (t) * 64 + poff)
#define STB(bufptr, c, t) GLOAD16((bufptr) + (c) * 4096 + ldsw, B + (size_t)(c) * 64 * 1024 + (t) * 64 + poff)

__device__ __forceinline__ void gemm8_core(
    const u16* __restrict__ A, const u16* __restrict__ B,
    u16* As0, u16* As1, u16* Bs0, u16* Bs1, float4v acc[8][4]) {
  const int tid = threadIdx.x;
  const int lane = tid & 63, wid = tid >> 6;
  const int wr = wid >> 2, wc = wid & 3;
  const int l15 = lane & 15, g = lane >> 4;
  const int poff = (wid * 8 + (lane >> 3)) * 1024 + ((lane & 7) ^ ((lane >> 3) & 7)) * 8;
  const int ldsw = wid * 512;

  // prologue: tile0 full (8), tile1 B all + A chunks {0,2} (6)
  STB(Bs0, 0, 0); STB(Bs0, 1, 0); STB(Bs0, 2, 0); STB(Bs0, 3, 0);
  STA(As0, 0, 0); STA(As0, 1, 0); STA(As0, 2, 0); STA(As0, 3, 0);
  STB(Bs1, 0, 1); STB(Bs1, 1, 1); STB(Bs1, 2, 1); STB(Bs1, 3, 1);
  STA(As1, 0, 1); STA(As1, 2, 1);
  WAITVM6();
  BAR();

  for (int i = 0; i < 8; ++i) {
    const int t1 = 2 * i + 1, t2 = 2 * i + 2, t3 = 2 * i + 3;
    const bool more = (i < 7);
    short8v bF[2][4];
    short8v aF0, aF0k, aF1, aF1k;
    // PH1
    READB(Bs0); READA(As0, 0);
    STA(As1, 1, t1); STA(As1, 3, t1);
    BAR(); MFMA16(0); BAR();
    // PH2
    READA(As0, 2);
    if (more) { STB(Bs0, 0, t2); STB(Bs0, 1, t2); }
    BAR(); MFMA16(2); BAR();
    // PH3
    READA(As0, 4);
    if (more) { STB(Bs0, 2, t2); STB(Bs0, 3, t2); }
    BAR(); MFMA16(4); BAR();
    // PH4
    READA(As0, 6);
    if (more) { STA(As0, 0, t2); STA(As0, 2, t2); }
    BAR(); MFMA16(6);
    if (more) { WAITVM6(); } else { WAITVM0(); }
    BAR();
    // PH5
    READB(Bs1); READA(As1, 0);
    if (more) { STA(As0, 1, t2); STA(As0, 3, t2); }
    BAR(); MFMA16(0); BAR();
    // PH6
    READA(As1, 2);
    if (more) { STB(Bs1, 0, t3); STB(Bs1, 1, t3); }
    BAR(); MFMA16(2); BAR();
    // PH7
    READA(As1, 4);
    if (more) { STB(Bs1, 2, t3); STB(Bs1, 3, t3); }
    BAR(); MFMA16(4); BAR();
    // PH8
    READA(As1, 6);
    if (more) { STA(As1, 0, t3); STA(As1, 2, t3); }
    BAR(); MFMA16(6);
    if (more) { WAITVM6(); }
    BAR();
  }
}

#define ZERO_ACC8(acc)                                           \
  _Pragma("unroll") for (int i_ = 0; i_ < 8; ++i_)               \
  _Pragma("unroll") for (int j_ = 0; j_ < 4; ++j_)               \
      acc[i_][j_] = (float4v){0.f, 0.f, 0.f, 0.f};

// ---------------------------------------------------------------------------
// fp32 -> bf16 convert of x, k-PERMUTED columns
// ---------------------------------------------------------------------------
__global__ void __launch_bounds__(256) k_conv(const float* __restrict__ in,
                                              u16* __restrict__ out) {
  const int i = blockIdx.x * 256 + threadIdx.x;
  float4v v = ((const float4v*)in)[i];
  const int row = i >> 8;
  const int c = (i & 255) * 4;
  ushort4v o;
  o[0] = f2bf(v[0]); o[1] = f2bf(v[1]); o[2] = f2bf(v[2]); o[3] = f2bf(v[3]);
  *(ushort4v*)(out + (size_t)row * 1024 + permp(c)) = o;
}

// ---------------------------------------------------------------------------
// transpose+convert weights: in [R][C] f32 -> out [C][R] bf16, R-dim PERMUTED
// ---------------------------------------------------------------------------
__global__ void __launch_bounds__(256) k_transpose(const float* __restrict__ in,
                                                   u16* __restrict__ out, int R, int C) {
  __shared__ u16 tile[64][65];
  const int nbc = C >> 6;
  const int bc = blockIdx.x % nbc, br = blockIdx.x / nbc;
  const int r0 = br * 64, c0 = bc * 64;
  const int t = threadIdx.x;
  const int lr = t >> 4;
  const int lc = (t & 15) * 4;
#pragma unroll
  for (int p = 0; p < 4; ++p) {
    const int r = p * 16 + lr;
    float4v v = *(const float4v*)(in + (size_t)(r0 + r) * C + c0 + lc);
    tile[r][lc + 0] = f2bf(v[0]); tile[r][lc + 1] = f2bf(v[1]);
    tile[r][lc + 2] = f2bf(v[2]); tile[r][lc + 3] = f2bf(v[3]);
  }
  __syncthreads();
#pragma unroll
  for (int p = 0; p < 4; ++p) {
    const int c = p * 16 + lr;
    ushort4v o;
    o[0] = tile[lc + 0][c]; o[1] = tile[lc + 1][c];
    o[2] = tile[lc + 2][c]; o[3] = tile[lc + 3][c];
    *(ushort4v*)(out + (size_t)(c0 + c) * R + permp(r0 + lc)) = o;
  }
}

// ---------------------------------------------------------------------------
// GEMM1 (8-phase): h1 = x@W1 + b1 -> q / k_t / non_att
// ---------------------------------------------------------------------------
__global__ void __launch_bounds__(512, 2) k_gemm1n(
    const u16* __restrict__ xb, const u16* __restrict__ w1t,
    const float* __restrict__ bias1, u16* __restrict__ qbuf,
    u16* __restrict__ ktb, float* __restrict__ dout) {
  __shared__ u16 As[2][16384], Bs[2][16384];
  const int wg = (blockIdx.x & 7) * 192 + (blockIdx.x >> 3);   // 1536 wgs
  const int mt = wg / 12, nt = wg % 12;
  float4v acc[8][4];
  ZERO_ACC8(acc);
  gemm8_core(xb + (size_t)mt * 256 * 1024, w1t + (size_t)nt * 256 * 1024,
             As[0], As[1], Bs[0], Bs[1], acc);
  const int lane = threadIdx.x & 63, wid = threadIdx.x >> 6;
  const int wr = wid >> 2, wc = wid & 3;
  const int l15 = lane & 15, g = lane >> 4;
  const int region = nt >> 2;
#pragma unroll
  for (int m = 0; m < 8; ++m) {
    const int rb = mt * 256 + wr * 128 + m * 16 + 4 * g;
#pragma unroll
    for (int j = 0; j < 4; ++j) {
      const int cg = nt * 256 + wc * 64 + j * 16 + l15;
      const float bia = bias1[cg];
      if (region == 0) {
#pragma unroll
        for (int r = 0; r < 4; ++r)
          qbuf[(size_t)(rb + r) * 1024 + cg] = f2bf(fmap(acc[m][j][r] + bia));
      } else if (region == 1) {
        const int rc = cg - 1024;
        ushort4v pk;
#pragma unroll
        for (int r = 0; r < 4; ++r) pk[r] = f2bf(fmap(acc[m][j][r] + bia));
        *(ushort4v*)(ktb + (size_t)rc * 32768 + rb) = pk;
      } else {
        const int rc = cg - 2048;
#pragma unroll
        for (int r = 0; r < 4; ++r)
          dout[(size_t)(rb + r) * 1024 + rc] = acc[m][j][r] + bia;
      }
    }
  }
}

// ---------------------------------------------------------------------------
// GEMM2 (8-phase): v = x@Wv + bv -> v_t [dim][N]
// ---------------------------------------------------------------------------
__global__ void __launch_bounds__(512, 2) k_gemm2n(
    const u16* __restrict__ xb, const u16* __restrict__ wvt,
    const float* __restrict__ biasv, u16* __restrict__ vtb) {
  __shared__ u16 As[2][16384], Bs[2][16384];
  const int wg = (blockIdx.x & 7) * 64 + (blockIdx.x >> 3);    // 512 wgs
  const int mt = wg >> 2, nt = wg & 3;
  float4v acc[8][4];
  ZERO_ACC8(acc);
  gemm8_core(xb + (size_t)mt * 256 * 1024, wvt + (size_t)nt * 256 * 1024,
             As[0], As[1], Bs[0], Bs[1], acc);
  const int lane = threadIdx.x & 63, wid = threadIdx.x >> 6;
  const int wr = wid >> 2, wc = wid & 3;
  const int l15 = lane & 15, g = lane >> 4;
#pragma unroll
  for (int m = 0; m < 8; ++m) {
    const int rb = mt * 256 + wr * 128 + m * 16 + 4 * g;
#pragma unroll
    for (int j = 0; j < 4; ++j) {
      const int cg = nt * 256 + wc * 64 + j * 16 + l15;
      const float bia = biasv[cg];
      ushort4v pk;
#pragma unroll
      for (int r = 0; r < 4; ++r) pk[r] = f2bf(acc[m][j][r] + bia);
      *(ushort4v*)(vtb + (size_t)cg * 32768 + rb) = pk;
    }
  }
}

// ---------------------------------------------------------------------------
// kv partials (old core): per (head, K-chunk of 1024) 128x128 GEMM
// ---------------------------------------------------------------------------
__global__ void __launch_bounds__(256) k_kvpart(
    const u16* __restrict__ ktb, const u16* __restrict__ vtb, float* __restrict__ part) {
  __shared__ u16 Al[128 * 64], Bl[128 * 64];
  const int h = blockIdx.x >> 5, ch = blockIdx.x & 31;
  float4v acc[4][4];
  ZERO_ACC4(acc);
  gemm_core(ktb + (size_t)h * 128 * 32768, 32768,
            vtb + (size_t)h * 128 * 32768, 32768, 0, 0, ch * 1024, 16, Al, Bl, acc);
  float* o = part + (size_t)(h * 32 + ch) * 16384;
  const int lane = threadIdx.x & 63, wid = threadIdx.x >> 6;
  const int wr = wid >> 1, wc = wid & 1;
#pragma unroll
  for (int i = 0; i < 4; ++i) {
    const int rb = wr * 64 + i * 16 + 4 * (lane >> 4);
#pragma unroll
    for (int j = 0; j < 4; ++j) {
      const int cg = wc * 64 + j * 16 + (lane & 15);
#pragma unroll
      for (int r = 0; r < 4; ++r) o[(size_t)(rb + r) * 128 + cg] = acc[i][j][r];
    }
  }
}

__global__ void __launch_bounds__(128) k_kvred(const float* __restrict__ part,
                                               u16* __restrict__ kvt) {
  const int b = blockIdx.x;
  const int h = b >> 7, kd = b & 127;
  const int vd = threadIdx.x;
  const float* p = part + (size_t)h * 32 * 16384 + (size_t)kd * 128 + vd;
  float s = 0.f;
#pragma unroll
  for (int c = 0; c < 32; ++c) s += p[(size_t)c * 16384];
  kvt[(size_t)(h * 128 + vd) * 128 + kd] = f2bf(s);
}

__global__ void __launch_bounds__(256) k_ksum(const u16* __restrict__ ktb,
                                              float* __restrict__ ksum) {
  const int b = blockIdx.x;
  const int t = threadIdx.x;
  const u16* row = ktb + (size_t)b * 32768;
  float s = 0.f;
#pragma unroll
  for (int i = 0; i < 16; ++i) {
    short8v v = *(const short8v*)(row + (size_t)(i * 256 + t) * 8);
#pragma unroll
    for (int e = 0; e < 8; ++e) s += bf2f((u16)v[e]);
  }
  __shared__ float red[256];
  red[t] = s;
  __syncthreads();
  for (int off = 128; off > 0; off >>= 1) {
    if (t < off) red[t] += red[t + off];
    __syncthreads();
  }
  if (t == 0) ksum[b] = red[0];
}

// ---------------------------------------------------------------------------
// att = (q @ kv) / (q . k_sum); writes att k-PERMUTED (consumed by gemmo)
// ---------------------------------------------------------------------------
__global__ void __launch_bounds__(256) k_attn(
    const u16* __restrict__ q, const u16* __restrict__ kvt,
    const float* __restrict__ ksum, u16* __restrict__ att) {
  __shared__ u16 qlds[128 * 128];
  __shared__ u16 blds[128 * 128];
  __shared__ float ksl[128];
  __shared__ float qkl[128];
  const int b = blockIdx.x;
  const int h = b >> 8, nt = b & 255;
  const int n0 = nt * 128;
  const int tid = threadIdx.x, lane = tid & 63, wid = tid >> 6;
  const int wr = wid >> 1, wc = wid & 1;
  const int sr = lane >> 4;
#pragma unroll
  for (int jj = 0; jj < 8; ++jj) {
    const int rb = wid * 32 + jj * 4;
    const int srcslot = (lane & 15) ^ ((rb + (lane >> 4)) & 15);
    GLOAD16(qlds + rb * 128, q + (size_t)(n0 + rb + sr) * 1024 + h * 128 + srcslot * 8);
    GLOAD16(blds + rb * 128, kvt + (size_t)(h * 128 + rb + sr) * 128 + srcslot * 8);
  }
  if (tid < 128) ksl[tid] = ksum[h * 128 + tid];
  __syncthreads();
  if (tid < 128) {
    float s = 0.f;
    const int rsw = tid & 15;
#pragma unroll
    for (int ii = 0; ii < 16; ++ii) {
      const int slot = ii ^ rsw;
      short8v v = *(const short8v*)((const char*)qlds + tid * 256 + slot * 16);
#pragma unroll
      for (int e = 0; e < 8; ++e) s += bf2f((u16)v[e]) * ksl[ii * 8 + e];
    }
    qkl[tid] = (s == 0.f) ? 1e-5f : s;
  }
  float4v acc[4][4];
  ZERO_ACC4(acc);
  const int swz = (lane & 15) << 4;
  const int g4 = 4 * (lane >> 4);
#pragma unroll
  for (int kk = 0; kk < 128; kk += 32) {
    const int c0 = 2 * (kk + g4);
    short8v af[4], bfr[4];
#pragma unroll
    for (int i = 0; i < 4; ++i) {
      const char* pa = (const char*)(qlds + (wr * 64 + i * 16 + (lane & 15)) * 128);
      short4v a0 = *(const short4v*)(pa + (c0 ^ swz));
      short4v a1 = *(const short4v*)(pa + ((c0 + 32) ^ swz));
      af[i] = __builtin_shufflevector(a0, a1, 0, 1, 2, 3, 4, 5, 6, 7);
      const char* pb = (const char*)(blds + (wc * 64 + i * 16 + (lane & 15)) * 128);
      short4v b0 = *(const short4v*)(pb + (c0 ^ swz));
      short4v b1 = *(const short4v*)(pb + ((c0 + 32) ^ swz));
      bfr[i] = __builtin_shufflevector(b0, b1, 0, 1, 2, 3, 4, 5, 6, 7);
    }
#pragma unroll
    for (int i = 0; i < 4; ++i)
#pragma unroll
      for (int j = 0; j < 4; ++j)
        acc[i][j] = __builtin_amdgcn_mfma_f32_16x16x32_bf16(af[i], bfr[j], acc[i][j], 0, 0, 0);
  }
  __syncthreads();
#pragma unroll
  for (int i = 0; i < 4; ++i) {
    const int rl = wr * 64 + i * 16 + 4 * (lane >> 4);
#pragma unroll
    for (int j = 0; j < 4; ++j) {
      const int cl = wc * 64 + j * 16 + (lane & 15);
      const int pc = permp(h * 128 + cl);
#pragma unroll
      for (int r = 0; r < 4; ++r) {
        const float v = acc[i][j][r] / qkl[rl + r];
        att[(size_t)(n0 + rl + r) * 1024 + pc] = f2bf(v);
      }
    }
  }
}

// ---------------------------------------------------------------------------
// GEMMo (8-phase): out = non_att(in d_out) + att@Wo + bo
// ---------------------------------------------------------------------------
__global__ void __launch_bounds__(512, 2) k_gemmon(
    const u16* __restrict__ attb, const u16* __restrict__ wot,
    const float* __restrict__ biaso, float* __restrict__ dout) {
  __shared__ u16 As[2][16384], Bs[2][16384];
  const int wg = (blockIdx.x & 7) * 64 + (blockIdx.x >> 3);    // 512 wgs
  const int mt = wg >> 2, nt = wg & 3;
  float4v acc[8][4];
  ZERO_ACC8(acc);
  gemm8_core(attb + (size_t)mt * 256 * 1024, wot + (size_t)nt * 256 * 1024,
             As[0], As[1], Bs[0], Bs[1], acc);
  const int lane = threadIdx.x & 63, wid = threadIdx.x >> 6;
  const int wr = wid >> 2, wc = wid & 3;
  const int l15 = lane & 15, g = lane >> 4;
#pragma unroll
  for (int m = 0; m < 8; ++m) {
    const int rb = mt * 256 + wr * 128 + m * 16 + 4 * g;
#pragma unroll
    for (int j = 0; j < 4; ++j) {
      const int cg = nt * 256 + wc * 64 + j * 16 + l15;
      const float bia = biaso[cg];
#pragma unroll
      for (int r = 0; r < 4; ++r) {
        const size_t idx = (size_t)(rb + r) * 1024 + cg;
        dout[idx] = dout[idx] + acc[m][j][r] + bia;
      }
    }
  }
}

// ---------------------------------------------------------------------------
extern "C" void kernel_launch(void* const* d_in, const int* in_sizes, int n_in,
                              void* d_out, int out_size, void* d_ws, size_t ws_size,
                              hipStream_t stream) {
  const float* x  = (const float*)d_in[0];
  const float* W1 = (const float*)d_in[1];
  const float* b1 = (const float*)d_in[2];
  const float* Wv = (const float*)d_in[3];
  const float* bv = (const float*)d_in[4];
  const float* Wo = (const float*)d_in[5];
  const float* bo = (const float*)d_in[6];
  float* out = (float*)d_out;

  const size_t N = 32768;
  u16* xb  = (u16*)d_ws;                    // x bf16 perm-k [N][1024]
  u16* qb  = xb  + N * 1024;                // q (then att, perm-k) [N][1024]
  u16* ktb = qb  + N * 1024;                // k_t [8*128][N]
  u16* vtb = ktb + N * 1024;                // v_t [8*128][N]
  u16* w1t = vtb + N * 1024;                // W1^T bf16 perm-k [3072][1024]
  u16* wvt = w1t + (size_t)3072 * 1024;     // Wv^T perm-k
  u16* wot = wvt + (size_t)1024 * 1024;     // Wo^T perm-k
  float* part = (float*)(wot + (size_t)1024 * 1024);  // kv partials
  u16* kvt = (u16*)(part + (size_t)8 * 32 * 16384);   // kv_t [h][vd][kd]
  float* ksum = (float*)(kvt + (size_t)8 * 16384);    // k_sum [8][128]

  k_conv<<<32768, 256, 0, stream>>>(x, xb);
  k_transpose<<<768, 256, 0, stream>>>(W1, w1t, 1024, 3072);
  k_transpose<<<256, 256, 0, stream>>>(Wv, wvt, 1024, 1024);
  k_transpose<<<256, 256, 0, stream>>>(Wo, wot, 1024, 1024);
  k_gemm1n<<<1536, 512, 0, stream>>>(xb, w1t, b1, qb, ktb, out);
  k_gemm2n<<<512, 512, 0, stream>>>(xb, wvt, bv, vtb);
  k_kvpart<<<256, 256, 0, stream>>>(ktb, vtb, part);
  k_ksum<<<1024, 256, 0, stream>>>(ktb, ksum);
  k_kvred<<<1024, 128, 0, stream>>>(part, kvt);
  k_attn<<<2048, 256, 0, stream>>>(qb, kvt, ksum, qb);
  k_gemmon<<<512, 512, 0, stream>>>(qb, wot, bo, out);
}